// Round 3
// baseline (2556.396 us; speedup 1.0000x reference)
//
#include <hip/hip_runtime.h>
#include <hip/hip_bf16.h>

#define N_NODES 50000
#define N_EDGES 800000
#define F_IN    768
#define H_DIM   256
#define N_B     32
#define N_G     4
#define C1      1280
#define C2      640
#define LDA     40   // padded LDS row stride in u16 (32 data + 8 pad) -> 2-way banks

typedef unsigned short u16;
typedef unsigned int u32;
typedef __bf16 bf16x8 __attribute__((ext_vector_type(8)));
typedef float f32x4 __attribute__((ext_vector_type(4)));

__device__ inline u16 f2b(float f) {
    u32 u = __builtin_bit_cast(u32, f);
    u += 0x7fffu + ((u >> 16) & 1u);   // RNE (finite values)
    return (u16)(u >> 16);
}
__device__ inline float b2f(u16 h) {
    u32 u = ((u32)h) << 16;
    return __builtin_bit_cast(float, u);
}
__device__ inline u32 pack2(float a, float b) {
    return (u32)f2b(a) | ((u32)f2b(b) << 16);
}

// ---------------- CSR build ----------------

__global__ void count_deg_kernel(const int* __restrict__ dst, int* __restrict__ deg, int n_edges) {
    int e = blockIdx.x * blockDim.x + threadIdx.x;
    if (e < n_edges) atomicAdd(&deg[dst[e]], 1);
}

// scan pass 1: per-block (1024-wide) totals
__global__ __launch_bounds__(1024) void scan1_kernel(const int* __restrict__ deg,
                                                     int* __restrict__ bsum, int n) {
    __shared__ int ws[16];
    int tid = threadIdx.x, lane = tid & 63, wid = tid >> 6;
    int i = blockIdx.x * 1024 + tid;
    int x = (i < n) ? deg[i] : 0;
#pragma unroll
    for (int off = 32; off; off >>= 1) x += __shfl_xor(x, off, 64);
    if (lane == 0) ws[wid] = x;
    __syncthreads();
    if (tid == 0) {
        int s = 0;
#pragma unroll
        for (int w = 0; w < 16; w++) s += ws[w];
        bsum[blockIdx.x] = s;
    }
}

// scan pass 2: exclusive scan of block totals (nb <= 64), also writes row_start[n]=total
__global__ __launch_bounds__(64) void scan2_kernel(int* __restrict__ bsum, int nb,
                                                   int* __restrict__ row_start, int n) {
    int lane = threadIdx.x;
    int x = (lane < nb) ? bsum[lane] : 0;
    int v = x;
#pragma unroll
    for (int off = 1; off < 64; off <<= 1) {
        int t = __shfl_up(v, off, 64);
        if (lane >= off) v += t;
    }
    if (lane < nb) bsum[lane] = v - x;  // exclusive
    if (lane == 63) row_start[n] = v;   // grand total
}

// scan pass 3: local exclusive scan + block offset; also dinv
__global__ __launch_bounds__(1024) void scan3_kernel(const int* __restrict__ deg,
                                                     const int* __restrict__ bsum,
                                                     int* __restrict__ row_start,
                                                     int* __restrict__ cursor,
                                                     float* __restrict__ dinv, int n) {
    __shared__ int ws[16];
    int tid = threadIdx.x, lane = tid & 63, wid = tid >> 6;
    int i = blockIdx.x * 1024 + tid;
    int x = (i < n) ? deg[i] : 0;
    int v = x;
#pragma unroll
    for (int off = 1; off < 64; off <<= 1) {
        int t = __shfl_up(v, off, 64);
        if (lane >= off) v += t;
    }
    if (lane == 63) ws[wid] = v;
    __syncthreads();
    if (wid == 0) {
        int s = (lane < 16) ? ws[lane] : 0;
#pragma unroll
        for (int off = 1; off < 16; off <<= 1) {
            int t = __shfl_up(s, off, 64);
            if (lane >= off) s += t;
        }
        if (lane < 16) ws[lane] = s;
    }
    __syncthreads();
    if (i < n) {
        int excl = bsum[blockIdx.x] + (wid ? ws[wid - 1] : 0) + (v - x);
        row_start[i] = excl;
        cursor[i] = excl;
        dinv[i] = rsqrtf((float)(x + 1));  // self-loop included
    }
}

__global__ void fill_csr_kernel(const int* __restrict__ src, const int* __restrict__ dst,
                                int* __restrict__ cursor, int* __restrict__ csr_src, int n_edges) {
    int e = blockIdx.x * blockDim.x + threadIdx.x;
    if (e < n_edges) {
        int d = dst[e];
        int pos = atomicAdd(&cursor[d], 1);
        csr_src[pos] = src[e];
    }
}

// ---------------- weight prep: W[K][256] fp32 -> Wt[256][K] bf16 ----------------

__global__ void prep_w_kernel(const float* __restrict__ W, u16* __restrict__ Wt, int K) {
    int idx = blockIdx.x * blockDim.x + threadIdx.x;
    if (idx >= K * 256) return;
    int k = idx >> 8, n = idx & 255;
    Wt[(size_t)n * K + k] = f2b(W[idx]);
}

// ---------------- MFMA GEMM: C[i][c] = bf16( dinv[i] * sum_k A[i][k]*W[k][c] ) --------
// A: [n,K] (fp32 or bf16, row-major), Wt: [256][K] bf16 (transposed), C: [n,256] bf16.
// 64x256 tile, BK=32, 256 threads; double-buffered LDS + 1-step register prefetch,
// ONE barrier per K-step. Padded LDS rows (stride 40 u16) for 2-way (free) banking.

__global__ __launch_bounds__(256) void gemm_mfma_kernel(const void* __restrict__ Aptr, int a_fp32,
                                                        const u16* __restrict__ Wt,
                                                        const float* __restrict__ dinv,
                                                        u16* __restrict__ Cout, int n, int K) {
    __shared__ u16 As[2 * 64 * LDA] __attribute__((aligned(16)));    // 2 x 5 KiB
    __shared__ u16 Bs[2 * 256 * LDA] __attribute__((aligned(16)));   // 2 x 20 KiB
    int tid = threadIdx.x;
    int row0 = blockIdx.x * 64;
    int wid = tid >> 6, lane = tid & 63;
    int mlane = lane & 15, kg = lane >> 4;

    int ra = tid >> 2;                 // 0..63
    int koffa = (tid & 3) << 3;        // 0,8,16,24
    int rga = row0 + ra; if (rga >= n) rga = n - 1;
    const float* Af = (const float*)Aptr;
    const u16*  Ab = (const u16*)Aptr;

    f32x4 acc[4][4];
#pragma unroll
    for (int a = 0; a < 4; a++)
#pragma unroll
        for (int b = 0; b < 4; b++)
#pragma unroll
            for (int c = 0; c < 4; c++) acc[a][b][c] = 0.f;

    int nk = K >> 5;
    int4 stA, stB0, stB1, stB2, stB3;

    // staged loaders (issue global loads; conversion for fp32 path sits behind the
    // compiler-placed vmcnt wait, i.e. at consume time)
    auto loadA = [&](int k0, int4& d) {
        if (a_fp32) {
            const float* s = Af + (size_t)rga * K + k0 + koffa;
            float4 f0 = *(const float4*)s;
            float4 f1 = *(const float4*)(s + 4);
            d.x = (int)pack2(f0.x, f0.y);
            d.y = (int)pack2(f0.z, f0.w);
            d.z = (int)pack2(f1.x, f1.y);
            d.w = (int)pack2(f1.z, f1.w);
        } else {
            d = *(const int4*)(Ab + (size_t)rga * K + k0 + koffa);
        }
    };
    auto loadB = [&](int k0) {
        stB0 = *(const int4*)(Wt + (size_t)(ra +   0) * K + k0 + koffa);
        stB1 = *(const int4*)(Wt + (size_t)(ra +  64) * K + k0 + koffa);
        stB2 = *(const int4*)(Wt + (size_t)(ra + 128) * K + k0 + koffa);
        stB3 = *(const int4*)(Wt + (size_t)(ra + 192) * K + k0 + koffa);
    };
    auto writeStage = [&](int buf) {
        *(int4*)&As[buf * (64 * LDA) + ra * LDA + koffa] = stA;
        u16* bb = &Bs[buf * (256 * LDA)];
        *(int4*)&bb[(ra +   0) * LDA + koffa] = stB0;
        *(int4*)&bb[(ra +  64) * LDA + koffa] = stB1;
        *(int4*)&bb[(ra + 128) * LDA + koffa] = stB2;
        *(int4*)&bb[(ra + 192) * LDA + koffa] = stB3;
    };

    // prologue: stage k-step 0 into buf 0; prefetch k-step 1 into regs
    loadA(0, stA); loadB(0);
    writeStage(0);
    if (nk > 1) { loadA(32, stA); loadB(32); }
    __syncthreads();

    int cur = 0;
    for (int t = 0; t < nk; t++) {
        // frag reads from current buffer (issued first; MFMA below waits lgkm on these)
        const u16* ab = &As[cur * (64 * LDA)];
        const u16* bb = &Bs[cur * (256 * LDA)];
        bf16x8 af[4], bfv[4];
#pragma unroll
        for (int mi = 0; mi < 4; mi++)
            af[mi] = *(const bf16x8*)&ab[(mi * 16 + mlane) * LDA + kg * 8];
#pragma unroll
        for (int ni = 0; ni < 4; ni++)
            bfv[ni] = *(const bf16x8*)&bb[(wid * 64 + ni * 16 + mlane) * LDA + kg * 8];
        // write prefetched step t+1 into the other buffer (vmcnt wait for loads issued
        // a full iteration ago lands here), then issue loads for t+2
        if (t + 1 < nk) {
            writeStage(cur ^ 1);
            if (t + 2 < nk) { loadA((t + 2) << 5, stA); loadB((t + 2) << 5); }
        }
#pragma unroll
        for (int mi = 0; mi < 4; mi++)
#pragma unroll
            for (int ni = 0; ni < 4; ni++)
                acc[mi][ni] = __builtin_amdgcn_mfma_f32_16x16x32_bf16(af[mi], bfv[ni], acc[mi][ni], 0, 0, 0);
        __syncthreads();   // single barrier per K-step
        cur ^= 1;
    }
    // epilogue: C/D layout col=lane&15, row=(lane>>4)*4+reg
#pragma unroll
    for (int mi = 0; mi < 4; mi++) {
        int rbase = row0 + mi * 16 + kg * 4;
#pragma unroll
        for (int r = 0; r < 4; r++) {
            int row = rbase + r;
            if (row < n) {
                float s = dinv[row];
#pragma unroll
                for (int ni = 0; ni < 4; ni++) {
                    int col = wid * 64 + ni * 16 + mlane;
                    Cout[(size_t)row * H_DIM + col] = f2b(acc[mi][ni][r] * s);
                }
            }
        }
    }
}

// ---------------- Aggregation: out[i] = maybe_relu(dinv[i]*(Ht[i] + sum_j Ht[j]) + b) --------
// 4 nodes per 256-thread block (one wave per node, no cross-wave interaction):
// 64-thread blocks cap at ~16 workgroups/CU (half occupancy); 4-wave blocks reach 32 waves/CU.

__global__ __launch_bounds__(256) void aggregate_kernel(const u16* __restrict__ Ht,
                                                        const int* __restrict__ row_start,
                                                        const int* __restrict__ csr_src,
                                                        const float* __restrict__ dinv,
                                                        const float* __restrict__ bias,
                                                        u16* __restrict__ out, int do_relu) {
    int i = blockIdx.x * 4 + (threadIdx.x >> 6);
    if (i >= N_NODES) return;
    int c4 = (threadIdx.x & 63) << 2;
    ushort4 sv = *(const ushort4*)(Ht + (size_t)i * H_DIM + c4);
    float a0 = b2f(sv.x), a1 = b2f(sv.y), a2 = b2f(sv.z), a3 = b2f(sv.w);
    int s = row_start[i], e = row_start[i + 1];
    for (int p = s; p < e; p++) {
        int j = csr_src[p];
        ushort4 v = *(const ushort4*)(Ht + (size_t)j * H_DIM + c4);
        a0 += b2f(v.x); a1 += b2f(v.y); a2 += b2f(v.z); a3 += b2f(v.w);
    }
    float di = dinv[i];
    float4 b = *(const float4*)(bias + c4);
    float o0 = a0 * di + b.x, o1 = a1 * di + b.y, o2 = a2 * di + b.z, o3 = a3 * di + b.w;
    if (do_relu) {
        o0 = fmaxf(o0, 0.f); o1 = fmaxf(o1, 0.f);
        o2 = fmaxf(o2, 0.f); o3 = fmaxf(o3, 0.f);
    }
    ushort4 ov = make_ushort4(f2b(o0), f2b(o1), f2b(o2), f2b(o3));
    *(ushort4*)(out + (size_t)i * H_DIM + c4) = ov;
}

// ---------------- Pooling ----------------
// batch is sorted: each block takes a contiguous node chunk, accumulates per-channel in a
// register, flushes to global with one atomicAdd per (segment boundary, channel).

__global__ __launch_bounds__(256) void pool_kernel(const u16* __restrict__ h3,
                                                   const int* __restrict__ batch,
                                                   float* __restrict__ concat, int g) {
    int tid = threadIdx.x;  // channel 0..255
    int per = (N_NODES + (int)gridDim.x - 1) / (int)gridDim.x;
    int start = blockIdx.x * per;
    int end = min(N_NODES, start + per);
    if (start >= end) return;
    float acc = 0.f;
    int cur = batch[start];
    for (int i = start; i < end; i++) {
        int b = batch[i];
        if (b != cur) {
            atomicAdd(&concat[cur * C1 + g * H_DIM + tid], acc);
            acc = 0.f;
            cur = b;
        }
        acc += b2f(h3[(size_t)i * H_DIM + tid]);
    }
    atomicAdd(&concat[cur * C1 + g * H_DIM + tid], acc);
}

// per-batch node counts via binary search on sorted batch array
__global__ __launch_bounds__(64) void count_kernel(const int* __restrict__ batch,
                                                   float* __restrict__ cnt, int g) {
    __shared__ int bound[N_B + 1];
    int t = threadIdx.x;
    if (t <= N_B) {
        int lo = 0, hi = N_NODES;
        while (lo < hi) {
            int mid = (lo + hi) >> 1;
            if (batch[mid] < t) lo = mid + 1; else hi = mid;
        }
        bound[t] = lo;
    }
    __syncthreads();
    if (t < N_B) cnt[g * N_B + t] = (float)(bound[t + 1] - bound[t]);
}

__global__ void pool_div_kernel(float* __restrict__ concat, const float* __restrict__ cnt) {
    int idx = blockIdx.x * blockDim.x + threadIdx.x;  // 4*32*256
    int g = idx >> 13;
    int r = idx & 8191;
    int b = r >> 8;
    int f = r & 255;
    float c = fmaxf(cnt[g * N_B + b], 1.f);
    concat[b * C1 + g * H_DIM + f] /= c;
}

// ---------------- MLP head (fp32, tiny) ----------------

__global__ void xc_kernel(const float* __restrict__ x_code, const float* __restrict__ Wc,
                          const float* __restrict__ bc, float* __restrict__ concat) {
    int idx = blockIdx.x * blockDim.x + threadIdx.x;  // 32*256
    int b = idx >> 8, c = idx & 255;
    float acc = bc[c];
    for (int k = 0; k < F_IN; k++) acc += x_code[b * F_IN + k] * Wc[k * H_DIM + c];
    concat[b * C1 + 4 * H_DIM + c] = fmaxf(acc, 0.f);
}

__global__ void mlp1_kernel(const float* __restrict__ concat, const float* __restrict__ Wl1,
                            const float* __restrict__ bl1, float* __restrict__ hmid) {
    int idx = blockIdx.x * blockDim.x + threadIdx.x;  // 32*640
    int b = idx / C2, c = idx % C2;
    float acc = bl1[c];
    for (int k = 0; k < C1; k++) acc += concat[b * C1 + k] * Wl1[k * C2 + c];
    hmid[b * C2 + c] = fmaxf(acc, 0.f);
}

__global__ void mlp2_kernel(const float* __restrict__ hmid, const float* __restrict__ Wl2,
                            const float* __restrict__ bl2, float* __restrict__ out) {
    int idx = threadIdx.x;  // 64 = 32*2
    if (idx < N_B * 2) {
        int b = idx >> 1, c = idx & 1;
        float acc = bl2[c];
        for (int k = 0; k < C2; k++) acc += hmid[b * C2 + k] * Wl2[k * 2 + c];
        out[b * 2 + c] = acc;
    }
}

// ---------------- Launch ----------------

extern "C" void kernel_launch(void* const* d_in, const int* in_sizes, int n_in,
                              void* d_out, int out_size, void* d_ws, size_t ws_size,
                              hipStream_t stream) {
    const float* x_g[N_G];
    const int* ei[N_G];
    const int* batch[N_G];
    for (int g = 0; g < N_G; g++) {
        x_g[g]   = (const float*)d_in[3 * g + 0];
        ei[g]    = (const int*)d_in[3 * g + 1];
        batch[g] = (const int*)d_in[3 * g + 2];
    }
    const float* x_code = (const float*)d_in[12];
    const float* W1 = (const float*)d_in[13];
    const float* b1 = (const float*)d_in[14];
    const float* W2 = (const float*)d_in[15];
    const float* b2 = (const float*)d_in[16];
    const float* W3 = (const float*)d_in[17];
    const float* b3 = (const float*)d_in[18];
    const float* Wc = (const float*)d_in[19];
    const float* bc = (const float*)d_in[20];
    const float* Wl1 = (const float*)d_in[21];
    const float* bl1 = (const float*)d_in[22];
    const float* Wl2 = (const float*)d_in[23];
    const float* bl2 = (const float*)d_in[24];
    float* out = (float*)d_out;

    char* p = (char*)d_ws;
    auto alloc = [&](size_t bytes) -> void* {
        void* q = (void*)p;
        p += (bytes + 255) & ~(size_t)255;
        return q;
    };
    u16*   bufA      = (u16*)alloc((size_t)N_NODES * H_DIM * 2);
    u16*   bufB      = (u16*)alloc((size_t)N_NODES * H_DIM * 2);
    u16*   Wt1       = (u16*)alloc((size_t)H_DIM * F_IN * 2);
    u16*   Wt2       = (u16*)alloc((size_t)H_DIM * H_DIM * 2);
    u16*   Wt3       = (u16*)alloc((size_t)H_DIM * H_DIM * 2);
    int*   row_start = (int*)alloc((size_t)(N_NODES + 1) * 4);
    int*   cursor    = (int*)alloc((size_t)N_NODES * 4);
    int*   csr_src   = (int*)alloc((size_t)N_EDGES * 4);
    int*   deg       = (int*)alloc((size_t)N_NODES * 4);
    float* dinv      = (float*)alloc((size_t)N_NODES * 4);
    float* concat    = (float*)alloc((size_t)N_B * C1 * 4);
    float* cnt       = (float*)alloc((size_t)N_G * N_B * 4);
    float* hmid      = (float*)alloc((size_t)N_B * C2 * 4);
    int*   bsum      = (int*)alloc((size_t)64 * 4);

    hipMemsetAsync(concat, 0, (size_t)N_B * C1 * 4, stream);

    // weight prep (bf16 transposed)
    prep_w_kernel<<<(F_IN * 256 + 255) / 256, 256, 0, stream>>>(W1, Wt1, F_IN);
    prep_w_kernel<<<(H_DIM * 256 + 255) / 256, 256, 0, stream>>>(W2, Wt2, H_DIM);
    prep_w_kernel<<<(H_DIM * 256 + 255) / 256, 256, 0, stream>>>(W3, Wt3, H_DIM);

    dim3 gemm_grid((N_NODES + 63) / 64);
    dim3 agg_grid((N_NODES + 3) / 4);
    int nb_scan = (N_NODES + 1023) / 1024;  // 49

    for (int g = 0; g < N_G; g++) {
        const int* src = ei[g];
        const int* dst = ei[g] + N_EDGES;
        hipMemsetAsync(deg, 0, (size_t)N_NODES * 4, stream);
        count_deg_kernel<<<(N_EDGES + 255) / 256, 256, 0, stream>>>(dst, deg, N_EDGES);
        scan1_kernel<<<nb_scan, 1024, 0, stream>>>(deg, bsum, N_NODES);
        scan2_kernel<<<1, 64, 0, stream>>>(bsum, nb_scan, row_start, N_NODES);
        scan3_kernel<<<nb_scan, 1024, 0, stream>>>(deg, bsum, row_start, cursor, dinv, N_NODES);
        fill_csr_kernel<<<(N_EDGES + 255) / 256, 256, 0, stream>>>(src, dst, cursor, csr_src, N_EDGES);

        // layer 1: A = x (fp32), K=768
        gemm_mfma_kernel<<<gemm_grid, 256, 0, stream>>>(x_g[g], 1, Wt1, dinv, bufA, N_NODES, F_IN);
        aggregate_kernel<<<agg_grid, 256, 0, stream>>>(bufA, row_start, csr_src, dinv, b1, bufB, 1);
        // layer 2: A = bufB (bf16), K=256
        gemm_mfma_kernel<<<gemm_grid, 256, 0, stream>>>(bufB, 0, Wt2, dinv, bufA, N_NODES, H_DIM);
        aggregate_kernel<<<agg_grid, 256, 0, stream>>>(bufA, row_start, csr_src, dinv, b2, bufB, 1);
        // layer 3: K=256, no relu
        gemm_mfma_kernel<<<gemm_grid, 256, 0, stream>>>(bufB, 0, Wt3, dinv, bufA, N_NODES, H_DIM);
        aggregate_kernel<<<agg_grid, 256, 0, stream>>>(bufA, row_start, csr_src, dinv, b3, bufB, 0);

        pool_kernel<<<2048, 256, 0, stream>>>(bufB, batch[g], concat, g);
        count_kernel<<<1, 64, 0, stream>>>(batch[g], cnt, g);
    }

    pool_div_kernel<<<(N_G * N_B * H_DIM) / 256, 256, 0, stream>>>(concat, cnt);
    xc_kernel<<<(N_B * H_DIM) / 256, 256, 0, stream>>>(x_code, Wc, bc, concat);
    mlp1_kernel<<<(N_B * C2) / 256, 256, 0, stream>>>(concat, Wl1, bl1, hmid);
    mlp2_kernel<<<1, 64, 0, stream>>>(hmid, Wl2, bl2, out);
}

// Round 4
// 2285.720 us; speedup vs baseline: 1.1184x; 1.1184x over previous
//
#include <hip/hip_runtime.h>
#include <hip/hip_bf16.h>

#define N_NODES 50000
#define N_EDGES 800000
#define F_IN    768
#define H_DIM   256
#define N_B     32
#define N_G     4
#define C1      1280
#define C2      640

typedef unsigned short u16;
typedef unsigned int u32;
typedef __bf16 bf16x8 __attribute__((ext_vector_type(8)));
typedef float f32x4 __attribute__((ext_vector_type(4)));

__device__ inline u16 f2b(float f) {
    u32 u = __builtin_bit_cast(u32, f);
    u += 0x7fffu + ((u >> 16) & 1u);   // RNE (finite values)
    return (u16)(u >> 16);
}
__device__ inline float b2f(u16 h) {
    u32 u = ((u32)h) << 16;
    return __builtin_bit_cast(float, u);
}
__device__ inline u32 pack2(float a, float b) {
    return (u32)f2b(a) | ((u32)f2b(b) << 16);
}

// ---------------- CSR build ----------------

__global__ void count_deg_kernel(const int* __restrict__ dst, int* __restrict__ deg, int n_edges) {
    int e = blockIdx.x * blockDim.x + threadIdx.x;
    if (e < n_edges) atomicAdd(&deg[dst[e]], 1);
}

// scan pass 1: per-block (1024-wide) totals
__global__ __launch_bounds__(1024) void scan1_kernel(const int* __restrict__ deg,
                                                     int* __restrict__ bsum, int n) {
    __shared__ int ws[16];
    int tid = threadIdx.x, lane = tid & 63, wid = tid >> 6;
    int i = blockIdx.x * 1024 + tid;
    int x = (i < n) ? deg[i] : 0;
#pragma unroll
    for (int off = 32; off; off >>= 1) x += __shfl_xor(x, off, 64);
    if (lane == 0) ws[wid] = x;
    __syncthreads();
    if (tid == 0) {
        int s = 0;
#pragma unroll
        for (int w = 0; w < 16; w++) s += ws[w];
        bsum[blockIdx.x] = s;
    }
}

// scan pass 2: exclusive scan of block totals (nb <= 64), also writes row_start[n]=total
__global__ __launch_bounds__(64) void scan2_kernel(int* __restrict__ bsum, int nb,
                                                   int* __restrict__ row_start, int n) {
    int lane = threadIdx.x;
    int x = (lane < nb) ? bsum[lane] : 0;
    int v = x;
#pragma unroll
    for (int off = 1; off < 64; off <<= 1) {
        int t = __shfl_up(v, off, 64);
        if (lane >= off) v += t;
    }
    if (lane < nb) bsum[lane] = v - x;  // exclusive
    if (lane == 63) row_start[n] = v;   // grand total
}

// scan pass 3: local exclusive scan + block offset; also dinv
__global__ __launch_bounds__(1024) void scan3_kernel(const int* __restrict__ deg,
                                                     const int* __restrict__ bsum,
                                                     int* __restrict__ row_start,
                                                     int* __restrict__ cursor,
                                                     float* __restrict__ dinv, int n) {
    __shared__ int ws[16];
    int tid = threadIdx.x, lane = tid & 63, wid = tid >> 6;
    int i = blockIdx.x * 1024 + tid;
    int x = (i < n) ? deg[i] : 0;
    int v = x;
#pragma unroll
    for (int off = 1; off < 64; off <<= 1) {
        int t = __shfl_up(v, off, 64);
        if (lane >= off) v += t;
    }
    if (lane == 63) ws[wid] = v;
    __syncthreads();
    if (wid == 0) {
        int s = (lane < 16) ? ws[lane] : 0;
#pragma unroll
        for (int off = 1; off < 16; off <<= 1) {
            int t = __shfl_up(s, off, 64);
            if (lane >= off) s += t;
        }
        if (lane < 16) ws[lane] = s;
    }
    __syncthreads();
    if (i < n) {
        int excl = bsum[blockIdx.x] + (wid ? ws[wid - 1] : 0) + (v - x);
        row_start[i] = excl;
        cursor[i] = excl;
        dinv[i] = rsqrtf((float)(x + 1));  // self-loop included
    }
}

__global__ void fill_csr_kernel(const int* __restrict__ src, const int* __restrict__ dst,
                                int* __restrict__ cursor, int* __restrict__ csr_src, int n_edges) {
    int e = blockIdx.x * blockDim.x + threadIdx.x;
    if (e < n_edges) {
        int d = dst[e];
        int pos = atomicAdd(&cursor[d], 1);
        csr_src[pos] = src[e];
    }
}

// ---------------- weight prep: W[K][256] fp32 -> Wt[256][K] bf16 ----------------

__global__ void prep_w_kernel(const float* __restrict__ W, u16* __restrict__ Wt, int K) {
    int idx = blockIdx.x * blockDim.x + threadIdx.x;
    if (idx >= K * 256) return;
    int k = idx >> 8, n = idx & 255;
    Wt[(size_t)n * K + k] = f2b(W[idx]);
}

// ---------------- MFMA GEMM: C[i][c] = bf16( dinv[i] * sum_k A[i][k]*W[k][c] ) --------
// A: [n,K] row-major (fp32 if AFP32 else bf16); Wt: [256][K] bf16; C: [n,256] bf16.
// 64x256 tile, BK=32, 256 threads, wave = 64-col stripe.
// A: LDS double-buffer (2x4KB) with XOR swizzle (((row>>1)&3)<<3 in u16) -> free 2-way banks.
// B: loaded DIRECTLY global->registers (Wt is L2-resident; a wave's 4 kg-groups fully
//    consume each 64B line), ping-pong b0/b1 one K-step ahead. One barrier per K-step.

template<int K, bool AFP32>
__global__ __launch_bounds__(256) void gemm_mfma_kernel(const void* __restrict__ Aptr,
                                                        const u16* __restrict__ Wt,
                                                        const float* __restrict__ dinv,
                                                        u16* __restrict__ Cout, int n) {
    constexpr int NK = K / 32;  // 24 or 8 (even)
    __shared__ u16 As[2 * 2048] __attribute__((aligned(16)));  // 2 x 4 KiB
    int tid = threadIdx.x;
    int row0 = blockIdx.x * 64;
    int wid = tid >> 6, lane = tid & 63;
    int mlane = lane & 15, kg = lane >> 4;

    int ra = tid >> 2;                 // 0..63 (A row staged by this thread)
    int qa = tid & 3;                  // k-quad (8 u16 each)
    int rga = row0 + ra; if (rga >= n) rga = n - 1;
    const float* Af = (const float*)Aptr;
    const u16*  Ab = (const u16*)Aptr;
    int awr = (ra * 32 + qa * 8) ^ (((ra >> 1) & 3) << 3);   // swizzled u16 index

    const u16* wtb = Wt + (size_t)(wid * 64 + mlane) * K + kg * 8;

    f32x4 acc[4][4];
#pragma unroll
    for (int a = 0; a < 4; a++)
#pragma unroll
        for (int b = 0; b < 4; b++)
#pragma unroll
            for (int c = 0; c < 4; c++) acc[a][b][c] = 0.f;

    float4 rF0, rF1; int4 rA;
    auto loadA = [&](int s) {                 // raw global load only (no convert)
        int k0 = (s < NK ? s : NK - 1) * 32;
        if constexpr (AFP32) {
            const float* sp = Af + (size_t)rga * K + k0 + qa * 8;
            rF0 = *(const float4*)sp;
            rF1 = *(const float4*)(sp + 4);
        } else {
            rA = *(const int4*)(Ab + (size_t)rga * K + k0 + qa * 8);
        }
    };
    auto writeA = [&](int buf) {              // convert (fp32 path) + LDS write
        int4 v;
        if constexpr (AFP32) {
            v.x = (int)pack2(rF0.x, rF0.y); v.y = (int)pack2(rF0.z, rF0.w);
            v.z = (int)pack2(rF1.x, rF1.y); v.w = (int)pack2(rF1.z, rF1.w);
        } else {
            v = rA;
        }
        *(int4*)&As[buf * 2048 + awr] = v;
    };
    auto loadB = [&](bf16x8* b, int s) {      // direct global->reg B fragments
        int k0 = (s < NK ? s : NK - 1) * 32;
#pragma unroll
        for (int ni = 0; ni < 4; ni++)
            b[ni] = *(const bf16x8*)(wtb + (size_t)ni * 16 * K + k0);
    };
    auto readA = [&](bf16x8* a, int buf) {
#pragma unroll
        for (int mi = 0; mi < 4; mi++) {
            int m = mi * 16 + mlane;
            a[mi] = *(const bf16x8*)&As[buf * 2048 + ((m * 32 + kg * 8) ^ (((m >> 1) & 3) << 3))];
        }
    };
    auto domfma = [&](bf16x8* a, bf16x8* b) {
#pragma unroll
        for (int mi = 0; mi < 4; mi++)
#pragma unroll
            for (int ni = 0; ni < 4; ni++)
                acc[mi][ni] = __builtin_amdgcn_mfma_f32_16x16x32_bf16(a[mi], b[ni], acc[mi][ni], 0, 0, 0);
    };

    bf16x8 b0[4], b1[4], af[4];
    // prologue: stage step 0 -> buf0; prefetch A(1) and B(0) into regs
    loadA(0); writeA(0);
    loadA(1);
    loadB(b0, 0);
    __syncthreads();

    for (int t = 0; t < NK; t += 2) {
        // even sub-step: compute from buf0
        readA(af, 0);
        writeA(1);                 // stage t+1 (regs loaded last sub-step)
        loadA(t + 2);              // issue A(t+2)
        loadB(b1, t + 1);          // issue B(t+1) -> consumed next sub-step
        domfma(af, b0);
        __syncthreads();
        // odd sub-step: compute from buf1
        readA(af, 1);
        writeA(0);                 // stage t+2
        loadA(t + 3);
        loadB(b0, t + 2);
        domfma(af, b1);
        __syncthreads();
    }

    // epilogue: C/D layout col=lane&15, row=(lane>>4)*4+reg
#pragma unroll
    for (int mi = 0; mi < 4; mi++) {
        int rbase = row0 + mi * 16 + kg * 4;
#pragma unroll
        for (int r = 0; r < 4; r++) {
            int row = rbase + r;
            if (row < n) {
                float s = dinv[row];
#pragma unroll
                for (int ni = 0; ni < 4; ni++) {
                    int col = wid * 64 + ni * 16 + mlane;
                    Cout[(size_t)row * H_DIM + col] = f2b(acc[mi][ni][r] * s);
                }
            }
        }
    }
}

// ---------------- Aggregation: out[i] = maybe_relu(dinv[i]*(Ht[i] + sum_j Ht[j]) + b) --------

__global__ __launch_bounds__(64) void aggregate_kernel(const u16* __restrict__ Ht,
                                                       const int* __restrict__ row_start,
                                                       const int* __restrict__ csr_src,
                                                       const float* __restrict__ dinv,
                                                       const float* __restrict__ bias,
                                                       u16* __restrict__ out, int do_relu) {
    int i = blockIdx.x;
    int c4 = threadIdx.x << 2;
    ushort4 sv = *(const ushort4*)(Ht + (size_t)i * H_DIM + c4);
    float a0 = b2f(sv.x), a1 = b2f(sv.y), a2 = b2f(sv.z), a3 = b2f(sv.w);
    int s = row_start[i], e = row_start[i + 1];
    for (int p = s; p < e; p++) {
        int j = csr_src[p];
        ushort4 v = *(const ushort4*)(Ht + (size_t)j * H_DIM + c4);
        a0 += b2f(v.x); a1 += b2f(v.y); a2 += b2f(v.z); a3 += b2f(v.w);
    }
    float di = dinv[i];
    float4 b = *(const float4*)(bias + c4);
    float o0 = a0 * di + b.x, o1 = a1 * di + b.y, o2 = a2 * di + b.z, o3 = a3 * di + b.w;
    if (do_relu) {
        o0 = fmaxf(o0, 0.f); o1 = fmaxf(o1, 0.f);
        o2 = fmaxf(o2, 0.f); o3 = fmaxf(o3, 0.f);
    }
    ushort4 ov = make_ushort4(f2b(o0), f2b(o1), f2b(o2), f2b(o3));
    *(ushort4*)(out + (size_t)i * H_DIM + c4) = ov;
}

// ---------------- Pooling ----------------
// batch is sorted: each block takes a contiguous node chunk, accumulates per-channel in a
// register, flushes to global with one atomicAdd per (segment boundary, channel).

__global__ __launch_bounds__(256) void pool_kernel(const u16* __restrict__ h3,
                                                   const int* __restrict__ batch,
                                                   float* __restrict__ concat, int g) {
    int tid = threadIdx.x;  // channel 0..255
    int per = (N_NODES + (int)gridDim.x - 1) / (int)gridDim.x;
    int start = blockIdx.x * per;
    int end = min(N_NODES, start + per);
    if (start >= end) return;
    float acc = 0.f;
    int cur = batch[start];
    for (int i = start; i < end; i++) {
        int b = batch[i];
        if (b != cur) {
            atomicAdd(&concat[cur * C1 + g * H_DIM + tid], acc);
            acc = 0.f;
            cur = b;
        }
        acc += b2f(h3[(size_t)i * H_DIM + tid]);
    }
    atomicAdd(&concat[cur * C1 + g * H_DIM + tid], acc);
}

// per-batch node counts via binary search on sorted batch array
__global__ __launch_bounds__(64) void count_kernel(const int* __restrict__ batch,
                                                   float* __restrict__ cnt, int g) {
    __shared__ int bound[N_B + 1];
    int t = threadIdx.x;
    if (t <= N_B) {
        int lo = 0, hi = N_NODES;
        while (lo < hi) {
            int mid = (lo + hi) >> 1;
            if (batch[mid] < t) lo = mid + 1; else hi = mid;
        }
        bound[t] = lo;
    }
    __syncthreads();
    if (t < N_B) cnt[g * N_B + t] = (float)(bound[t + 1] - bound[t]);
}

__global__ void pool_div_kernel(float* __restrict__ concat, const float* __restrict__ cnt) {
    int idx = blockIdx.x * blockDim.x + threadIdx.x;  // 4*32*256
    int g = idx >> 13;
    int r = idx & 8191;
    int b = r >> 8;
    int f = r & 255;
    float c = fmaxf(cnt[g * N_B + b], 1.f);
    concat[b * C1 + g * H_DIM + f] /= c;
}

// ---------------- MLP head (fp32, tiny) ----------------

__global__ void xc_kernel(const float* __restrict__ x_code, const float* __restrict__ Wc,
                          const float* __restrict__ bc, float* __restrict__ concat) {
    int idx = blockIdx.x * blockDim.x + threadIdx.x;  // 32*256
    int b = idx >> 8, c = idx & 255;
    float acc = bc[c];
    for (int k = 0; k < F_IN; k++) acc += x_code[b * F_IN + k] * Wc[k * H_DIM + c];
    concat[b * C1 + 4 * H_DIM + c] = fmaxf(acc, 0.f);
}

__global__ void mlp1_kernel(const float* __restrict__ concat, const float* __restrict__ Wl1,
                            const float* __restrict__ bl1, float* __restrict__ hmid) {
    int idx = blockIdx.x * blockDim.x + threadIdx.x;  // 32*640
    int b = idx / C2, c = idx % C2;
    float acc = bl1[c];
    for (int k = 0; k < C1; k++) acc += concat[b * C1 + k] * Wl1[k * C2 + c];
    hmid[b * C2 + c] = fmaxf(acc, 0.f);
}

__global__ void mlp2_kernel(const float* __restrict__ hmid, const float* __restrict__ Wl2,
                            const float* __restrict__ bl2, float* __restrict__ out) {
    int idx = threadIdx.x;  // 64 = 32*2
    if (idx < N_B * 2) {
        int b = idx >> 1, c = idx & 1;
        float acc = bl2[c];
        for (int k = 0; k < C2; k++) acc += hmid[b * C2 + k] * Wl2[k * 2 + c];
        out[b * 2 + c] = acc;
    }
}

// ---------------- Launch ----------------

extern "C" void kernel_launch(void* const* d_in, const int* in_sizes, int n_in,
                              void* d_out, int out_size, void* d_ws, size_t ws_size,
                              hipStream_t stream) {
    const float* x_g[N_G];
    const int* ei[N_G];
    const int* batch[N_G];
    for (int g = 0; g < N_G; g++) {
        x_g[g]   = (const float*)d_in[3 * g + 0];
        ei[g]    = (const int*)d_in[3 * g + 1];
        batch[g] = (const int*)d_in[3 * g + 2];
    }
    const float* x_code = (const float*)d_in[12];
    const float* W1 = (const float*)d_in[13];
    const float* b1 = (const float*)d_in[14];
    const float* W2 = (const float*)d_in[15];
    const float* b2 = (const float*)d_in[16];
    const float* W3 = (const float*)d_in[17];
    const float* b3 = (const float*)d_in[18];
    const float* Wc = (const float*)d_in[19];
    const float* bc = (const float*)d_in[20];
    const float* Wl1 = (const float*)d_in[21];
    const float* bl1 = (const float*)d_in[22];
    const float* Wl2 = (const float*)d_in[23];
    const float* bl2 = (const float*)d_in[24];
    float* out = (float*)d_out;

    char* p = (char*)d_ws;
    auto alloc = [&](size_t bytes) -> void* {
        void* q = (void*)p;
        p += (bytes + 255) & ~(size_t)255;
        return q;
    };
    u16*   bufA      = (u16*)alloc((size_t)N_NODES * H_DIM * 2);
    u16*   bufB      = (u16*)alloc((size_t)N_NODES * H_DIM * 2);
    u16*   Wt1       = (u16*)alloc((size_t)H_DIM * F_IN * 2);
    u16*   Wt2       = (u16*)alloc((size_t)H_DIM * H_DIM * 2);
    u16*   Wt3       = (u16*)alloc((size_t)H_DIM * H_DIM * 2);
    int*   row_start = (int*)alloc((size_t)(N_NODES + 1) * 4);
    int*   cursor    = (int*)alloc((size_t)N_NODES * 4);
    int*   csr_src   = (int*)alloc((size_t)N_EDGES * 4);
    int*   deg       = (int*)alloc((size_t)N_NODES * 4);
    float* dinv      = (float*)alloc((size_t)N_NODES * 4);
    float* concat    = (float*)alloc((size_t)N_B * C1 * 4);
    float* cnt       = (float*)alloc((size_t)N_G * N_B * 4);
    float* hmid      = (float*)alloc((size_t)N_B * C2 * 4);
    int*   bsum      = (int*)alloc((size_t)64 * 4);

    hipMemsetAsync(concat, 0, (size_t)N_B * C1 * 4, stream);

    // weight prep (bf16 transposed)
    prep_w_kernel<<<(F_IN * 256 + 255) / 256, 256, 0, stream>>>(W1, Wt1, F_IN);
    prep_w_kernel<<<(H_DIM * 256 + 255) / 256, 256, 0, stream>>>(W2, Wt2, H_DIM);
    prep_w_kernel<<<(H_DIM * 256 + 255) / 256, 256, 0, stream>>>(W3, Wt3, H_DIM);

    dim3 gemm_grid((N_NODES + 63) / 64);
    int nb_scan = (N_NODES + 1023) / 1024;  // 49

    for (int g = 0; g < N_G; g++) {
        const int* src = ei[g];
        const int* dst = ei[g] + N_EDGES;
        hipMemsetAsync(deg, 0, (size_t)N_NODES * 4, stream);
        count_deg_kernel<<<(N_EDGES + 255) / 256, 256, 0, stream>>>(dst, deg, N_EDGES);
        scan1_kernel<<<nb_scan, 1024, 0, stream>>>(deg, bsum, N_NODES);
        scan2_kernel<<<1, 64, 0, stream>>>(bsum, nb_scan, row_start, N_NODES);
        scan3_kernel<<<nb_scan, 1024, 0, stream>>>(deg, bsum, row_start, cursor, dinv, N_NODES);
        fill_csr_kernel<<<(N_EDGES + 255) / 256, 256, 0, stream>>>(src, dst, cursor, csr_src, N_EDGES);

        // layer 1: A = x (fp32), K=768
        gemm_mfma_kernel<F_IN, true><<<gemm_grid, 256, 0, stream>>>(x_g[g], Wt1, dinv, bufA, N_NODES);
        aggregate_kernel<<<N_NODES, 64, 0, stream>>>(bufA, row_start, csr_src, dinv, b1, bufB, 1);
        // layer 2: A = bufB (bf16), K=256
        gemm_mfma_kernel<H_DIM, false><<<gemm_grid, 256, 0, stream>>>(bufB, Wt2, dinv, bufA, N_NODES);
        aggregate_kernel<<<N_NODES, 64, 0, stream>>>(bufA, row_start, csr_src, dinv, b2, bufB, 1);
        // layer 3: K=256, no relu
        gemm_mfma_kernel<H_DIM, false><<<gemm_grid, 256, 0, stream>>>(bufB, Wt3, dinv, bufA, N_NODES);
        aggregate_kernel<<<N_NODES, 64, 0, stream>>>(bufA, row_start, csr_src, dinv, b3, bufB, 0);

        pool_kernel<<<2048, 256, 0, stream>>>(bufB, batch[g], concat, g);
        count_kernel<<<1, 64, 0, stream>>>(batch[g], cnt, g);
    }

    pool_div_kernel<<<(N_G * N_B * H_DIM) / 256, 256, 0, stream>>>(concat, cnt);
    xc_kernel<<<(N_B * H_DIM) / 256, 256, 0, stream>>>(x_code, Wc, bc, concat);
    mlp1_kernel<<<(N_B * C2) / 256, 256, 0, stream>>>(concat, Wl1, bl1, hmid);
    mlp2_kernel<<<1, 64, 0, stream>>>(hmid, Wl2, bl2, out);
}